// Round 4
// baseline (452.565 us; speedup 1.0000x reference)
//
#include <hip/hip_runtime.h>
#include <stdint.h>

// B=32, L1=L2=512, D=1024, fp32 in/out.
// sim: pre-split bf16 hi/lo (split done once in conv), 3-MFMA GEMM, no VALU
//      repack in the K-loop.
// PV GEMMs + attention probs: fp16 (2^-11 quant, was bf16 2^-8) for margin.
// ws layout (257.2 MiB of 512 MiB):
//   [0]      v1h  bf16 [B][L][D] (32Mi)    [32Mi]  v1l
//   [64Mi]   v2h                            [96Mi]  v2l
//   [128Mi]  v1t  f16 [B][D][L] (32Mi)     [160Mi] v2t
//   [192Mi]  sim  fp32 [B][L1][L2] (32Mi)
//   [224Mi]  A1   f16 [B][L1][L2] (16Mi)   [240Mi] A2t f16 [B][L2][L1]
//   [256Mi]  pmax fp32 [B][8][512] (512Ki) [+512Ki] psum

#define Bn 32
#define Ln 512
#define Dn 1024

typedef __attribute__((ext_vector_type(4))) float f32x4;
typedef __attribute__((ext_vector_type(4))) unsigned short u16x4;
typedef __attribute__((ext_vector_type(8))) __bf16 bf16x8;
typedef __attribute__((ext_vector_type(8))) _Float16 f16x8;
typedef __attribute__((ext_vector_type(4))) _Float16 f16x4;

__device__ __forceinline__ void async_cp16(const void* g, void* l) {
  __builtin_amdgcn_global_load_lds(
      (__attribute__((address_space(1))) void*)(g),
      (__attribute__((address_space(3))) void*)(l), 16, 0, 0);
}

// ---- fp32 -> {bf16 hi, bf16 lo} K-major + fp16 transposed ----
// grid (Dn/64=16, Ln/64=8, 2*Bn=64); z<32 -> v1, else v2
__global__ __launch_bounds__(256) void conv_split_t(
    const float* __restrict__ v1, const float* __restrict__ v2,
    unsigned short* __restrict__ v1h, unsigned short* __restrict__ v1l,
    unsigned short* __restrict__ v2h, unsigned short* __restrict__ v2l,
    _Float16* __restrict__ v1t, _Float16* __restrict__ v2t) {
  __shared__ float tile[64][65];
  const int z = blockIdx.z;
  const float* src = (z < Bn) ? v1 : v2;
  unsigned short* dh = (z < Bn) ? v1h : v2h;
  unsigned short* dl = (z < Bn) ? v1l : v2l;
  _Float16* dt = (z < Bn) ? v1t : v2t;
  const int b = z & 31;
  const int d0 = blockIdx.x << 6;
  const int l0 = blockIdx.y << 6;
  const int tid = threadIdx.x;
#pragma unroll
  for (int it = 0; it < 4; it++) {
    int lin = (it << 8) + tid;
    int l = lin >> 4;
    int d4 = (lin & 15) << 2;
    size_t base = (size_t)(b * Ln + l0 + l) * Dn + d0 + d4;
    f32x4 x = *(const f32x4*)(src + base);
    u16x4 h, lo;
#pragma unroll
    for (int e = 0; e < 4; e++) {
      unsigned int u = __float_as_uint(x[e]);
      h[e] = (unsigned short)(u >> 16);
      float hf = __uint_as_float(u & 0xFFFF0000u);
      lo[e] = (unsigned short)(__float_as_uint(x[e] - hf) >> 16);
    }
    *(u16x4*)(dh + base) = h;
    *(u16x4*)(dl + base) = lo;
    tile[l][d4] = x[0]; tile[l][d4 + 1] = x[1];
    tile[l][d4 + 2] = x[2]; tile[l][d4 + 3] = x[3];
  }
  __syncthreads();
#pragma unroll
  for (int it = 0; it < 4; it++) {
    int lin = (it << 8) + tid;
    int d = lin >> 4;
    int l4 = (lin & 15) << 2;
    f16x4 o;
    o[0] = (_Float16)tile[l4][d];     o[1] = (_Float16)tile[l4 + 1][d];
    o[2] = (_Float16)tile[l4 + 2][d]; o[3] = (_Float16)tile[l4 + 3][d];
    *(f16x4*)(dt + (size_t)(b * Dn + d0 + d) * Ln + l0 + l4) = o;
  }
}

// ---- sim[b][i][j] = hi.hi + hi.lo + lo.hi, pre-split operands ----
// 128x128 tile, BK=32, grid (4,4,32), 256 thr, 32 KB LDS.
__global__ __launch_bounds__(256) void sim_gemm3(
    const unsigned short* __restrict__ Ah_, const unsigned short* __restrict__ Al_,
    const unsigned short* __restrict__ Bh_, const unsigned short* __restrict__ Bl_,
    float* __restrict__ C) {
  __shared__ unsigned short AsH[4096], AsL[4096], BsH[4096], BsL[4096];
  const int b = blockIdx.z;
  const size_t boff = (size_t)b * Ln * Dn;
  float* Cb = C + (size_t)b * Ln * Ln;
  const int m0 = blockIdx.y << 7;
  const int n0 = blockIdx.x << 7;
  const int tid = threadIdx.x;
  const int lane = tid & 63;
  const int wave = tid >> 6;
  const int wrow = (wave >> 1) << 6;
  const int wcol = (wave & 1) << 6;

  const int srow = tid >> 2;
  const int skof = (tid & 3) << 3;
  const unsigned short* gah0 = Ah_ + boff + (size_t)(m0 + srow) * Dn + skof;
  const unsigned short* gah1 = gah0 + (size_t)64 * Dn;
  const unsigned short* gal0 = Al_ + boff + (size_t)(m0 + srow) * Dn + skof;
  const unsigned short* gal1 = gal0 + (size_t)64 * Dn;
  const unsigned short* gbh0 = Bh_ + boff + (size_t)(n0 + srow) * Dn + skof;
  const unsigned short* gbh1 = gbh0 + (size_t)64 * Dn;
  const unsigned short* gbl0 = Bl_ + boff + (size_t)(n0 + srow) * Dn + skof;
  const unsigned short* gbl1 = gbl0 + (size_t)64 * Dn;

  const int r = lane & 15;
  const int q = lane >> 4;

  const f32x4 zero4 = {0.f, 0.f, 0.f, 0.f};
  f32x4 acc[4][4];
#pragma unroll
  for (int i = 0; i < 4; i++)
#pragma unroll
    for (int j = 0; j < 4; j++) acc[i][j] = zero4;

  for (int k0 = 0; k0 < Dn; k0 += 32) {
    __syncthreads();
    async_cp16(gah0 + k0, AsH + (wave << 9));
    async_cp16(gah1 + k0, AsH + 2048 + (wave << 9));
    async_cp16(gal0 + k0, AsL + (wave << 9));
    async_cp16(gal1 + k0, AsL + 2048 + (wave << 9));
    async_cp16(gbh0 + k0, BsH + (wave << 9));
    async_cp16(gbh1 + k0, BsH + 2048 + (wave << 9));
    async_cp16(gbl0 + k0, BsL + (wave << 9));
    async_cp16(gbl1 + k0, BsL + 2048 + (wave << 9));
    __syncthreads();
    bf16x8 ah[4], al[4], bh[4], bl[4];
#pragma unroll
    for (int t = 0; t < 4; t++) {
      int oa = ((wrow + (t << 4) + r) << 5) + (q << 3);
      int ob = ((wcol + (t << 4) + r) << 5) + (q << 3);
      ah[t] = *(const bf16x8*)(AsH + oa);
      al[t] = *(const bf16x8*)(AsL + oa);
      bh[t] = *(const bf16x8*)(BsH + ob);
      bl[t] = *(const bf16x8*)(BsL + ob);
    }
#pragma unroll
    for (int tm = 0; tm < 4; tm++)
#pragma unroll
      for (int tn = 0; tn < 4; tn++) {
        acc[tm][tn] = __builtin_amdgcn_mfma_f32_16x16x32_bf16(
            ah[tm], bh[tn], acc[tm][tn], 0, 0, 0);
        acc[tm][tn] = __builtin_amdgcn_mfma_f32_16x16x32_bf16(
            ah[tm], bl[tn], acc[tm][tn], 0, 0, 0);
        acc[tm][tn] = __builtin_amdgcn_mfma_f32_16x16x32_bf16(
            al[tm], bh[tn], acc[tm][tn], 0, 0, 0);
      }
  }

#pragma unroll
  for (int tm = 0; tm < 4; tm++) {
    int rowb = m0 + wrow + (tm << 4) + (q << 2);
#pragma unroll
    for (int reg = 0; reg < 4; reg++) {
      int row = rowb + reg;
#pragma unroll
      for (int tn = 0; tn < 4; tn++) {
        int col = n0 + wcol + (tn << 4) + r;
        Cb[(size_t)row * Ln + col] = acc[tm][tn][reg];
      }
    }
  }
}

// ---- NT GEMM (fp16): C[b][m][n] = sum_k A[b][m][k]*B[b][n][k], fp32 out ----
__global__ __launch_bounds__(256) void gemm_nt_f16(
    const _Float16* __restrict__ A, const _Float16* __restrict__ Bm,
    float* __restrict__ C, const int* __restrict__ rowmask,
    int M, int N, int K) {
  __shared__ _Float16 As[128 * 32];
  __shared__ _Float16 Bs[128 * 32];
  const int b = blockIdx.z;
  const _Float16* Ab = A + (size_t)b * M * K;
  const _Float16* Bb = Bm + (size_t)b * N * K;
  float* Cb = C + (size_t)b * M * N;
  const int m0 = blockIdx.y << 7;
  const int n0 = blockIdx.x << 7;
  const int tid = threadIdx.x;
  const int lane = tid & 63;
  const int wave = tid >> 6;
  const int wrow = (wave >> 1) << 6;
  const int wcol = (wave & 1) << 6;

  const int srow = tid >> 2;
  const int skof = (tid & 3) << 3;
  const _Float16* ga0 = Ab + (size_t)(m0 + srow) * K + skof;
  const _Float16* ga1 = Ab + (size_t)(m0 + 64 + srow) * K + skof;
  const _Float16* gb0 = Bb + (size_t)(n0 + srow) * K + skof;
  const _Float16* gb1 = Bb + (size_t)(n0 + 64 + srow) * K + skof;

  const int r = lane & 15;
  const int q = lane >> 4;

  const f32x4 zero4 = {0.f, 0.f, 0.f, 0.f};
  f32x4 acc[4][4];
#pragma unroll
  for (int i = 0; i < 4; i++)
#pragma unroll
    for (int j = 0; j < 4; j++) acc[i][j] = zero4;

  for (int k0 = 0; k0 < K; k0 += 32) {
    __syncthreads();
    async_cp16(ga0 + k0, As + (wave << 9));
    async_cp16(ga1 + k0, As + 2048 + (wave << 9));
    async_cp16(gb0 + k0, Bs + (wave << 9));
    async_cp16(gb1 + k0, Bs + 2048 + (wave << 9));
    __syncthreads();
    f16x8 af[4], bf[4];
#pragma unroll
    for (int t = 0; t < 4; t++) {
      af[t] = *(const f16x8*)(As + ((wrow + (t << 4) + r) << 5) + (q << 3));
      bf[t] = *(const f16x8*)(Bs + ((wcol + (t << 4) + r) << 5) + (q << 3));
    }
#pragma unroll
    for (int tm = 0; tm < 4; tm++)
#pragma unroll
      for (int tn = 0; tn < 4; tn++)
        acc[tm][tn] = __builtin_amdgcn_mfma_f32_16x16x32_f16(
            af[tm], bf[tn], acc[tm][tn], 0, 0, 0);
  }

  const int* mb = rowmask ? rowmask + b * M : (const int*)0;
#pragma unroll
  for (int tm = 0; tm < 4; tm++) {
    int rowb = m0 + wrow + (tm << 4) + (q << 2);
#pragma unroll
    for (int reg = 0; reg < 4; reg++) {
      int row = rowb + reg;
      float mz = (mb && mb[row]) ? 0.f : 1.f;
#pragma unroll
      for (int tn = 0; tn < 4; tn++) {
        int col = n0 + wcol + (tn << 4) + r;
        Cb[(size_t)row * N + col] = acc[tm][tn][reg] * mz;
      }
    }
  }
}

// ---- softmax over j (contiguous), masked by v2_mask; out fp16 ----
__global__ __launch_bounds__(256) void row_softmax(
    const float* __restrict__ sim, const int* __restrict__ v2m,
    _Float16* __restrict__ A1) {
  const int row = (blockIdx.x << 2) + (threadIdx.x >> 6);
  const int lane = threadIdx.x & 63;
  const int b = row >> 9;
  const float* s = sim + (size_t)row * Ln;
  const int* mk = v2m + (b << 9);
  const float NEGINF = -__builtin_inff();
  float v[8];
  float mx = NEGINF;
#pragma unroll
  for (int t = 0; t < 8; t++) {
    int j = lane + (t << 6);
    float x = mk[j] ? NEGINF : s[j];
    v[t] = x;
    mx = fmaxf(mx, x);
  }
#pragma unroll
  for (int off = 32; off > 0; off >>= 1) mx = fmaxf(mx, __shfl_xor(mx, off));
  float sum = 0.f;
#pragma unroll
  for (int t = 0; t < 8; t++) {
    float e = (v[t] > NEGINF) ? __expf(v[t] - mx) : 0.f;
    v[t] = e;
    sum += e;
  }
#pragma unroll
  for (int off = 32; off > 0; off >>= 1) sum += __shfl_xor(sum, off);
  float rs = 1.f / sum;
  _Float16* o = A1 + (size_t)row * Ln;
#pragma unroll
  for (int t = 0; t < 8; t++) o[lane + (t << 6)] = (_Float16)(v[t] * rs);
}

// ---- column softmax phase 1: per-(64j x 64i)-tile max/sum partials ----
// grid (8 jc, 8 ic, 32 b). pmax/psum [B][8][512]
__global__ __launch_bounds__(256) void csm_part(
    const float* __restrict__ sim, const int* __restrict__ v1m,
    float* __restrict__ pmax, float* __restrict__ psum) {
  __shared__ float sm[4][64], ss[4][64];
  const int b = blockIdx.z;
  const int ic = blockIdx.y;
  const int i0 = ic << 6;
  const int j0 = blockIdx.x << 6;
  const int tx = threadIdx.x & 63;
  const int ty = threadIdx.x >> 6;
  const float* S = sim + (size_t)b * (Ln * Ln) + j0 + tx;
  const int* mk = v1m + (b << 9) + i0;
  const float NEGINF = -__builtin_inff();
  float x[16];
#pragma unroll
  for (int k = 0; k < 16; k++) {
    int il = (k << 2) + ty;
    float v = S[(size_t)(i0 + il) * Ln];
    x[k] = mk[il] ? NEGINF : v;
  }
  float m = NEGINF;
#pragma unroll
  for (int k = 0; k < 16; k++) m = fmaxf(m, x[k]);
  float s = 0.f;
#pragma unroll
  for (int k = 0; k < 16; k++) s += (x[k] > NEGINF) ? __expf(x[k] - m) : 0.f;
  sm[ty][tx] = m;
  ss[ty][tx] = s;
  __syncthreads();
  if (ty == 0) {
    float M = fmaxf(fmaxf(sm[0][tx], sm[1][tx]), fmaxf(sm[2][tx], sm[3][tx]));
    float Sv = 0.f;
#pragma unroll
    for (int p = 0; p < 4; p++)
      Sv += (sm[p][tx] > NEGINF) ? ss[p][tx] * __expf(sm[p][tx] - M) : 0.f;
    int idx = (((b << 3) + ic) << 9) + j0 + tx;
    pmax[idx] = M;
    psum[idx] = Sv;
  }
}

// ---- column softmax phase 2 (combine fused) + transposed fp16 write ----
// grid (8 jc, 8 ic, 32 b)
__global__ __launch_bounds__(256) void csm_write(
    const float* __restrict__ sim, const int* __restrict__ v1m,
    const float* __restrict__ pmax, const float* __restrict__ psum,
    _Float16* __restrict__ A2t) {
  __shared__ float cm[64], cr[64];
  __shared__ _Float16 Tc[64][66];
  const int b = blockIdx.z;
  const int i0 = blockIdx.y << 6;
  const int j0 = blockIdx.x << 6;
  const int tx = threadIdx.x & 63;
  const int ty = threadIdx.x >> 6;
  const float NEGINF = -__builtin_inff();
  if (threadIdx.x < 64) {
    int j = j0 + (int)threadIdx.x;
    float M = NEGINF;
    float mm[8], sv[8];
#pragma unroll
    for (int p = 0; p < 8; p++) {
      int idx = (((b << 3) + p) << 9) + j;
      mm[p] = pmax[idx];
      sv[p] = psum[idx];
      M = fmaxf(M, mm[p]);
    }
    float Sv = 0.f;
#pragma unroll
    for (int p = 0; p < 8; p++)
      Sv += (mm[p] > NEGINF) ? sv[p] * __expf(mm[p] - M) : 0.f;
    cm[threadIdx.x] = M;
    cr[threadIdx.x] = 1.f / Sv;
  }
  __syncthreads();
  const float* S = sim + (size_t)b * (Ln * Ln) + j0 + tx;
  const int* mk = v1m + (b << 9) + i0;
  const float cmx = cm[tx];
  const float cs = cr[tx];
#pragma unroll
  for (int k = 0; k < 16; k++) {
    int il = (k << 2) + ty;
    float x = S[(size_t)(i0 + il) * Ln];
    float e = mk[il] ? 0.f : __expf(x - cmx) * cs;
    Tc[tx][il] = (_Float16)e;
  }
  __syncthreads();
  _Float16* o = A2t + ((size_t)(b << 9) + j0) * Ln + i0;
#pragma unroll
  for (int t = 0; t < 4; t++) {
    int c = (t << 8) + (int)threadIdx.x;
    int j = c >> 4;
    int ch = c & 15;
    f16x4 v;
    v[0] = Tc[j][(ch << 2)];     v[1] = Tc[j][(ch << 2) + 1];
    v[2] = Tc[j][(ch << 2) + 2]; v[3] = Tc[j][(ch << 2) + 3];
    *(f16x4*)(o + (size_t)j * Ln + (ch << 2)) = v;
  }
}

extern "C" void kernel_launch(void* const* d_in, const int* in_sizes, int n_in,
                              void* d_out, int out_size, void* d_ws,
                              size_t ws_size, hipStream_t stream) {
  (void)in_sizes; (void)n_in; (void)out_size; (void)ws_size;
  const float* v1 = (const float*)d_in[0];
  const float* v2 = (const float*)d_in[1];
  const int* v1m = (const int*)d_in[2];
  const int* v2m = (const int*)d_in[3];
  float* out1 = (float*)d_out;
  float* out2 = out1 + (size_t)Bn * Ln * Dn;

  char* ws = (char*)d_ws;
  const size_t Mi = 1048576;
  unsigned short* v1h = (unsigned short*)(ws);
  unsigned short* v1l = (unsigned short*)(ws + 32 * Mi);
  unsigned short* v2h = (unsigned short*)(ws + 64 * Mi);
  unsigned short* v2l = (unsigned short*)(ws + 96 * Mi);
  _Float16* v1t = (_Float16*)(ws + 128 * Mi);
  _Float16* v2t = (_Float16*)(ws + 160 * Mi);
  float* sim = (float*)(ws + 192 * Mi);
  _Float16* A1 = (_Float16*)(ws + 224 * Mi);
  _Float16* A2t = (_Float16*)(ws + 240 * Mi);
  float* pmax = (float*)(ws + 256 * Mi);
  float* psum = (float*)(ws + 256 * Mi + 512 * 1024);

  dim3 blk(256);
  conv_split_t<<<dim3(16, 8, 64), blk, 0, stream>>>(v1, v2, v1h, v1l, v2h,
                                                    v2l, v1t, v2t);
  sim_gemm3<<<dim3(4, 4, 32), blk, 0, stream>>>(v1h, v1l, v2h, v2l, sim);
  row_softmax<<<dim3(4096), blk, 0, stream>>>(sim, v2m, A1);
  csm_part<<<dim3(8, 8, 32), blk, 0, stream>>>(sim, v1m, pmax, psum);
  csm_write<<<dim3(8, 8, 32), blk, 0, stream>>>(sim, v1m, pmax, psum, A2t);
  // attended_v1[b][i][d] = sum_j A1[i,j] v2t[d,j]; zero masked i rows
  gemm_nt_f16<<<dim3(8, 4, 32), blk, 0, stream>>>(A1, v2t, out1, v1m,
                                                  512, 1024, 512);
  // attended_v2[b][j][d] = sum_i A2t[j,i] v1t[d,i]; zero masked j rows
  gemm_nt_f16<<<dim3(8, 4, 32), blk, 0, stream>>>(A2t, v1t, out2, v2m,
                                                  512, 1024, 512);
}